// Round 4
// baseline (97.550 us; speedup 1.0000x reference)
//
#include <hip/hip_runtime.h>

// Upsample1d (linear kernel, reflect pad), stride-2 transposed depthwise FIR.
//   out[2m]   = 0.25*h[m-1] + 0.75*h[m]   (h[-1] := h[1])
//   out[2m+1] = 0.75*h[m]   + 0.25*h[m+1] (h[L]  := h[L-2])
// Taps hard-coded: _LINEAR_KERNEL*2 = [0.25, 0.75, 0.75, 0.25] (absmax 0.0
// verified in round 2).
//
// R1's per-tile pattern (fastest so far: f4 load + 2 L1-hit neighbor scalars
// + 2 f4 stores) kept EXACTLY, but each thread now walks 16 tiles with a
// grid-stride whose tile step (524288) is a multiple of tiles-per-row (2048):
// `pos` and the reflect-clamped neighbor indices are loop-invariant, so the
// inner loop is load/compute/store + constant pointer bump. 2048 blocks
// (8/CU), setup amortized 16x, unroll 4 for load pipelining.

constexpr int L    = 8192;
constexpr int TPR  = L / 4;            // 2048 f4-tiles per row
constexpr int NROW = 4096;             // B*C
constexpr int BLK  = 256;
constexpr int NBLK = 2048;             // 8 blocks/CU on 256 CUs
constexpr int NTHR = NBLK * BLK;       // 524288 threads
constexpr int ITER = (NROW * TPR) / NTHR;   // 16
constexpr int RSTEP = NTHR / TPR;      // 256 rows advanced per iteration

__global__ __launch_bounds__(256) void upsample1d_kernel(
    const float* __restrict__ h, float* __restrict__ out) {
    const int t0   = blockIdx.x * BLK + threadIdx.x;
    const int pos  = t0 & (TPR - 1);
    const int row0 = t0 >> 11;               // t0 / TPR
    const int i0   = pos << 2;

    // reflect: h[-1]=h[1], h[L]=h[L-2]; clamped indices, loop-invariant
    const int li = (pos > 0)       ? (i0 - 1) : 1;
    const int ri = (pos < TPR - 1) ? (i0 + 4) : (L - 2);

    const float* __restrict__ hp = h + (size_t)row0 * L;
    float* __restrict__ op = out + (size_t)row0 * 2 * L + ((size_t)i0 << 1);

#pragma unroll 4
    for (int it = 0; it < ITER; ++it) {
        const float4 v  = *reinterpret_cast<const float4*>(hp + i0);
        const float  lf = hp[li];
        const float  rt = hp[ri];

        float4 a, b;
        a.x = 0.25f * lf  + 0.75f * v.x;
        a.y = 0.75f * v.x + 0.25f * v.y;
        a.z = 0.25f * v.x + 0.75f * v.y;
        a.w = 0.75f * v.y + 0.25f * v.z;
        b.x = 0.25f * v.y + 0.75f * v.z;
        b.y = 0.75f * v.z + 0.25f * v.w;
        b.z = 0.25f * v.z + 0.75f * v.w;
        b.w = 0.75f * v.w + 0.25f * rt;

        *reinterpret_cast<float4*>(op)     = a;
        *reinterpret_cast<float4*>(op + 4) = b;

        hp += (size_t)RSTEP * L;
        op += (size_t)RSTEP * 2 * L;
    }
}

extern "C" void kernel_launch(void* const* d_in, const int* in_sizes, int n_in,
                              void* d_out, int out_size, void* d_ws, size_t ws_size,
                              hipStream_t stream) {
    const float* h = (const float*)d_in[0];
    float* out = (float*)d_out;
    upsample1d_kernel<<<dim3(NBLK), dim3(BLK), 0, stream>>>(h, out);
}

// Round 5
// 74.451 us; speedup vs baseline: 1.3103x; 1.3103x over previous
//
#include <hip/hip_runtime.h>

// Upsample1d (linear kernel, reflect pad), stride-2 transposed depthwise FIR.
//   out[2m]   = 0.25*h[m-1] + 0.75*h[m]   (h[-1] := h[1])
//   out[2m+1] = 0.75*h[m]   + 0.25*h[m+1] (h[L]  := h[L-2])
// Taps hard-coded (absmax 0.0 verified in round 2).
//
// R1 economics kept (32768 short-lived blocks, 1 contiguous f4 global load
// per thread), but the block's 4 KB input is staged in LDS so that:
//   - neighbor taps are LDS reads (global loads: 3 -> 1 per thread; only 2
//     edge scalars per BLOCK),
//   - each thread writes out-f4 tiles `t` and `t+256` (block-strided), so
//     BOTH store instructions are perfectly lane-contiguous (1 KB/instr) —
//     eliminating R1's 32B-stride gapped stores.
// This is the clean A/B for the store-gap theory R2 confounded.

constexpr int L = 8192;

__global__ __launch_bounds__(256) void upsample1d_kernel(
    const float* __restrict__ h, float* __restrict__ out) {
    __shared__ __align__(16) float lds[1026];   // 1024 main + left edge + right edge

    const int t = threadIdx.x;
    const int fbase = blockIdx.x << 10;         // first input float of this block
    const float* __restrict__ hr = h + (size_t)blockIdx.y * L + fbase;

    // stage 4 KB of input, 16B-aligned f4 per lane (perfectly coalesced)
    reinterpret_cast<float4*>(lds)[t] = reinterpret_cast<const float4*>(hr)[t];
    if (t == 0)   lds[1024] = (fbase > 0)        ? hr[-1]   : hr[1];     // h[-1]=h[1]
    if (t == 255) lds[1025] = (fbase + 1024 < L) ? hr[1024] : hr[1022];  // h[L]=h[L-2]
    __syncthreads();

    float* __restrict__ op = out + (size_t)blockIdx.y * 2 * L + 2 * fbase;

    // out tile A: local out-f4 index t  (covers input floats 2t-1 .. 2t+2)
    {
        const float em1 = (t == 0) ? lds[1024] : lds[2 * t - 1];
        const float e0 = lds[2 * t], e1 = lds[2 * t + 1], e2 = lds[2 * t + 2];
        float4 a;
        a.x = 0.25f * em1 + 0.75f * e0;
        a.y = 0.75f * e0  + 0.25f * e1;
        a.z = 0.25f * e0  + 0.75f * e1;
        a.w = 0.75f * e1  + 0.25f * e2;
        reinterpret_cast<float4*>(op)[t] = a;          // lane-contiguous 1 KB store
    }
    // out tile B: local out-f4 index 256+t (input floats 511+2t .. 514+2t)
    {
        const int base = 512 + 2 * t;
        const float em1 = lds[base - 1], e0 = lds[base], e1 = lds[base + 1];
        const float e2 = (t == 255) ? lds[1025] : lds[base + 2];
        float4 b;
        b.x = 0.25f * em1 + 0.75f * e0;
        b.y = 0.75f * e0  + 0.25f * e1;
        b.z = 0.25f * e0  + 0.75f * e1;
        b.w = 0.75f * e1  + 0.25f * e2;
        reinterpret_cast<float4*>(op + 1024)[t] = b;   // lane-contiguous 1 KB store
    }
}

extern "C" void kernel_launch(void* const* d_in, const int* in_sizes, int n_in,
                              void* d_out, int out_size, void* d_ws, size_t ws_size,
                              hipStream_t stream) {
    const float* h = (const float*)d_in[0];
    float* out = (float*)d_out;

    const int nrows = in_sizes[0] / L;        // B*C = 4096
    dim3 grid((L / 4) / 256, nrows);          // (8, 4096) — R1's proven shape

    upsample1d_kernel<<<grid, 256, 0, stream>>>(h, out);
}